// Round 13
// baseline (1792.228 us; speedup 1.0000x reference)
//
#include <hip/hip_runtime.h>

#define DD 64
#define EPSV 1e-5f
#define BINSZ 256      // nodes per bin
#define NBINMAX 256    // supports up to 65536 nodes

__device__ __forceinline__ float rlane_f(float v, int k) {
    return __int_as_float(__builtin_amdgcn_readlane(__float_as_int(v), k));
}

// ---------------------------------------------------------------------------
// Detect whether edge_index is int64 or int32 (JAX x64 flag ambiguity).
// ---------------------------------------------------------------------------
__global__ void detect_idx_kernel(const void* __restrict__ idx, int* __restrict__ flag,
                                  int nsample, int n_nodes) {
    const long long* p = (const long long*)idx;
    int bad = 0;
    for (int i = threadIdx.x; i < nsample; i += blockDim.x) {
        long long v = p[i];
        if (v < 0 || v >= (long long)n_nodes) bad = 1;
    }
    __shared__ int sbad;
    if (threadIdx.x == 0) sbad = 0;
    __syncthreads();
    if (bad) atomicOr(&sbad, 1);
    __syncthreads();
    if (threadIdx.x == 0) *flag = sbad ? 0 : 1;  // 1 => int64, 0 => int32
}

// ---------------------------------------------------------------------------
// Bin histogram: per-block LDS hist over 2*nbin coarse bins, then one global
// atomicAdd per (block,bin). dir0 keyed by t (mi), dir1 keyed by s (mo).
// ---------------------------------------------------------------------------
__global__ __launch_bounds__(512) void binhist_kernel(
    const void* __restrict__ idx, const int* __restrict__ flag,
    int* __restrict__ cnt, int nbin, int n_edges) {
    __shared__ int h[2 * NBINMAX];
    const int tid = threadIdx.x;
    for (int i = tid; i < 2 * nbin; i += 512) h[i] = 0;
    __syncthreads();
    const bool is64 = (*flag != 0);
    const long long* p64 = (const long long*)idx;
    const int*       p32 = (const int*)idx;
    int gid = blockIdx.x * 512 + tid;
    int stride = gridDim.x * 512;
    for (int ed = gid; ed < n_edges; ed += stride) {
        int s, t;
        if (is64) { s = (int)p64[ed]; t = (int)p64[n_edges + ed]; }
        else      { s = p32[ed];      t = p32[n_edges + ed]; }
        atomicAdd(&h[t >> 8], 1);
        atomicAdd(&h[nbin + (s >> 8)], 1);
    }
    __syncthreads();
    for (int i = tid; i < 2 * nbin; i += 512) {
        int v = h[i];
        if (v) atomicAdd(&cnt[i], v);
    }
}

// Single wave scans 2*nbin (<=512) bin counts -> base and cur.
__global__ void binscan_kernel(const int* __restrict__ cnt,
                               int* __restrict__ base, int* __restrict__ cur, int nb) {
    const int t = threadIdx.x;            // 64 threads
    const int C = (nb + 63) >> 6;         // <= 8
    const int b0 = t * C;
    int m = nb - b0; if (m > C) m = C; if (m < 0) m = 0;
    int v[8];
    int sum = 0;
    for (int i = 0; i < m; ++i) { v[i] = cnt[b0 + i]; sum += v[i]; }
    int s = sum;
    #pragma unroll
    for (int d = 1; d < 64; d <<= 1) { int u = __shfl_up(s, d, 64); if (t >= d) s += u; }
    int run = s - sum;  // exclusive prefix
    for (int i = 0; i < m; ++i) {
        base[b0 + i] = run;
        cur[b0 + i]  = run;
        run += v[i];
    }
}

// ---------------------------------------------------------------------------
// Binned scatter: slot = atomicAdd(cur[bin]) -> pay[slot] = {meta, w}.
// meta packs src (u16, n<=65535) + bin-local target (u8) at bits 16..23.
// With only 2*nbin cursors the bin regions fill sequentially in time ->
// active write window ~2KB/bin -> full 64B lines before eviction -> ~1x
// write amplification (vs 8x for the 50K-cursor CSR fill, measured 123MB).
// ---------------------------------------------------------------------------
__global__ __launch_bounds__(256) void binscatter_kernel(
    const void* __restrict__ idx, const float* __restrict__ e, const int* __restrict__ flag,
    int* __restrict__ cur, int2* __restrict__ pay, int nbin, int n_edges) {
    const bool is64 = (*flag != 0);
    const long long* p64 = (const long long*)idx;
    const int*       p32 = (const int*)idx;
    int gid = blockIdx.x * 256 + threadIdx.x;
    int stride = gridDim.x * 256;
    for (int ed = gid; ed < n_edges; ed += stride) {
        int s, t;
        if (is64) { s = (int)p64[ed]; t = (int)p64[n_edges + ed]; }
        else      { s = p32[ed];      t = p32[n_edges + ed]; }
        int wbits = __float_as_int(e[ed]);
        int slot0 = atomicAdd(&cur[t >> 8], 1);
        pay[slot0] = make_int2(s | ((t & 255) << 16), wbits);
        int slot1 = atomicAdd(&cur[nbin + (s >> 8)], 1);
        pay[slot1] = make_int2(t | ((s & 255) << 16), wbits);
    }
}

// ---------------------------------------------------------------------------
// Binned accumulate: one WG per (dir,bin). 64KB LDS accumulator for 256
// nodes x 64 feats; stream the bin's payload (coalesced), broadcast via
// readlane, LDS-atomic accumulate (bank = lane%32, 2-way free), then one
// coalesced write-out. Replaces per-node CSR + gather entirely.
// ---------------------------------------------------------------------------
__global__ __launch_bounds__(512) void binacc_kernel(
    const float* __restrict__ x, const int2* __restrict__ pay,
    const int* __restrict__ base, const int* __restrict__ cnt,
    float* __restrict__ mi, float* __restrict__ mo, int nbin, int n_nodes) {
    __shared__ float acc[BINSZ * DD];  // 64 KB
    const int tid = threadIdx.x;
    const int wg = blockIdx.x;                 // 0 .. 2*nbin-1
    const int dir = (wg >= nbin) ? 1 : 0;
    const int bin = dir ? wg - nbin : wg;

    for (int i = tid; i < BINSZ * DD; i += 512) acc[i] = 0.0f;
    __syncthreads();

    const int b0 = base[wg], c = cnt[wg];
    const int lane = tid & 63, wv = tid >> 6;  // 8 waves

    for (int off = wv * 64; off < c; off += 512) {
        int2 pl = make_int2(0, 0);
        if (off + lane < c) pl = pay[b0 + off + lane];
        const int m = min(64, c - off);
        #pragma unroll 4
        for (int j = 0; j < m; ++j) {
            int   meta = __builtin_amdgcn_readlane(pl.x, j);
            float w    = __int_as_float(__builtin_amdgcn_readlane(pl.y, j));
            int src = meta & 0xFFFF;
            int tl  = (meta >> 16) & 0xFF;
            atomicAdd(&acc[tl * DD + lane], w * x[src * DD + lane]);
        }
    }
    __syncthreads();

    float* dst = dir ? mo : mi;
    const int node0 = bin * BINSZ;
    int nfl = (n_nodes - node0);
    if (nfl > BINSZ) nfl = BINSZ;
    nfl *= DD;
    for (int i = tid; i < nfl; i += 512) dst[node0 * DD + i] = acc[i];
}

// ---------------------------------------------------------------------------
// Fallback atomic scatter (ws too small or n_nodes > 65535).
// ---------------------------------------------------------------------------
__global__ __launch_bounds__(256) void scatter_kernel(
    const float* __restrict__ x, const float* __restrict__ e,
    const void* __restrict__ idx, const int* __restrict__ flag,
    float* __restrict__ mi, float* __restrict__ mo, int n_edges) {
    const int lane  = threadIdx.x & 63;
    const int slot  = (blockIdx.x * blockDim.x + threadIdx.x) >> 6;
    const int nslot = (gridDim.x * blockDim.x) >> 6;
    const bool is64 = (*flag != 0);
    const long long* p64 = (const long long*)idx;
    const int*       p32 = (const int*)idx;
    for (int ed = slot; ed < n_edges; ed += nslot) {
        int s, t;
        if (is64) { s = (int)p64[ed]; t = (int)p64[n_edges + ed]; }
        else      { s = p32[ed];      t = p32[n_edges + ed]; }
        float w  = e[ed];
        unsafeAtomicAdd(&mi[t * DD + lane], w * x[s * DD + lane]);
        unsafeAtomicAdd(&mo[s * DD + lane], w * x[t * DD + lane]);
    }
}

// ---------------------------------------------------------------------------
// Fused 4-layer MLP v4 (measured <174us): no LDS, W columns streamed from
// global (L2-hot), h in registers via readlane.
// ---------------------------------------------------------------------------
#define NPW 13

template<int N>
__device__ __forceinline__ void accumG(const float* __restrict__ wcol,
                                       const float (&h)[N], float (&acc)[N]) {
    #pragma unroll 8
    for (int k = 0; k < 64; ++k) {
        float w = wcol[k * 64];
        #pragma unroll
        for (int m = 0; m < N; ++m) acc[m] = fmaf(w, rlane_f(h[m], k), acc[m]);
    }
}

__device__ __forceinline__ float ln_relu(float v, float g, float bt) {
    float s = v;
    #pragma unroll
    for (int off = 32; off; off >>= 1) s += __shfl_xor(s, off, 64);
    float mu = s * (1.0f / 64.0f);
    float d = v - mu;
    float s2 = d * d;
    #pragma unroll
    for (int off = 32; off; off >>= 1) s2 += __shfl_xor(s2, off, 64);
    float r = d * rsqrtf(s2 * (1.0f / 64.0f) + EPSV) * g + bt;
    return fmaxf(r, 0.0f);
}

__global__ __launch_bounds__(512) void fused_mlp4(
    const float* __restrict__ mi, const float* __restrict__ mo, const float* __restrict__ x,
    const float* __restrict__ W1, const float* __restrict__ b1, const float* __restrict__ g1, const float* __restrict__ bt1,
    const float* __restrict__ W2, const float* __restrict__ b2, const float* __restrict__ g2, const float* __restrict__ bt2,
    const float* __restrict__ W3, const float* __restrict__ b3, const float* __restrict__ g3, const float* __restrict__ bt3,
    const float* __restrict__ W4, const float* __restrict__ b4, const float* __restrict__ g4, const float* __restrict__ bt4,
    float* __restrict__ out, int n_nodes) {

    const int wid = threadIdx.x >> 6, lane = threadIdx.x & 63;
    const int gw = blockIdx.x * 8 + wid;
    const int ngroups = (n_nodes + NPW - 1) / NPW;  // 3847
    if (gw >= ngroups) return;
    const int n0 = gw * NPW;

    float hmi[NPW], hmo[NPW], hx[NPW];
    #pragma unroll
    for (int m = 0; m < NPW; ++m) {
        int n = n0 + m; if (n >= n_nodes) n = n_nodes - 1;
        hmi[m] = mi[n * DD + lane];
        hmo[m] = mo[n * DD + lane];
        hx[m]  = x[n * DD + lane];
    }

    float acc[NPW], h[NPW];

    {   // layer 1 (192-k: [mi | mo | x])
        float bj = b1[lane];
        #pragma unroll
        for (int m = 0; m < NPW; ++m) acc[m] = bj;
        accumG(W1 + lane,             hmi, acc);
        accumG(W1 + 64 * DD + lane,   hmo, acc);
        accumG(W1 + 128 * DD + lane,  hx,  acc);
        float gj = g1[lane], btj = bt1[lane];
        #pragma unroll
        for (int m = 0; m < NPW; ++m) h[m] = ln_relu(acc[m], gj, btj);
    }
    {
        float bj = b2[lane];
        #pragma unroll
        for (int m = 0; m < NPW; ++m) acc[m] = bj;
        accumG(W2 + lane, h, acc);
        float gj = g2[lane], btj = bt2[lane];
        #pragma unroll
        for (int m = 0; m < NPW; ++m) h[m] = ln_relu(acc[m], gj, btj);
    }
    {
        float bj = b3[lane];
        #pragma unroll
        for (int m = 0; m < NPW; ++m) acc[m] = bj;
        accumG(W3 + lane, h, acc);
        float gj = g3[lane], btj = bt3[lane];
        #pragma unroll
        for (int m = 0; m < NPW; ++m) h[m] = ln_relu(acc[m], gj, btj);
    }
    {
        float bj = b4[lane];
        #pragma unroll
        for (int m = 0; m < NPW; ++m) acc[m] = bj;
        accumG(W4 + lane, h, acc);
        float gj = g4[lane], btj = bt4[lane];
        #pragma unroll
        for (int m = 0; m < NPW; ++m) h[m] = ln_relu(acc[m], gj, btj);
    }

    #pragma unroll
    for (int m = 0; m < NPW; ++m) {
        int n = n0 + m;
        if (n < n_nodes) out[n * DD + lane] = h[m];
    }
}

// ---------------------------------------------------------------------------
extern "C" void kernel_launch(void* const* d_in, const int* in_sizes, int n_in,
                              void* d_out, int out_size, void* d_ws, size_t ws_size,
                              hipStream_t stream) {
    const float* x   = (const float*)d_in[0];
    const float* e   = (const float*)d_in[1];
    const void*  idx = d_in[2];
    const float* W1 = (const float*)d_in[3],  *b1 = (const float*)d_in[4],
               * g1 = (const float*)d_in[5],  *bt1 = (const float*)d_in[6];
    const float* W2 = (const float*)d_in[7],  *b2 = (const float*)d_in[8],
               * g2 = (const float*)d_in[9],  *bt2 = (const float*)d_in[10];
    const float* W3 = (const float*)d_in[11], *b3 = (const float*)d_in[12],
               * g3 = (const float*)d_in[13], *bt3 = (const float*)d_in[14];
    const float* W4 = (const float*)d_in[15], *b4 = (const float*)d_in[16],
               * g4 = (const float*)d_in[17], *bt4 = (const float*)d_in[18];
    float* out = (float*)d_out;

    const int n_nodes = in_sizes[0] / DD;   // 50000
    const int n_edges = in_sizes[1];        // 1000000
    const int nbin = (n_nodes + BINSZ - 1) / BINSZ;  // 196

    // ws layout: mi | mo | flag(16B) | pay(2*E int2) | cnt | base | cur  (~41.6MB)
    float* mi = (float*)d_ws;
    float* mo = mi + (size_t)n_nodes * DD;
    int*  flag = (int*)(mo + (size_t)n_nodes * DD);
    char* p = (char*)(flag + 4);
    int2* pay = (int2*)p;             p += (size_t)2 * n_edges * sizeof(int2);
    int* cnt  = (int*)p;              p += (size_t)2 * nbin * 4;
    int* base = (int*)p;              p += (size_t)2 * nbin * 4;
    int* cur  = (int*)p;              p += (size_t)2 * nbin * 4;
    const size_t need = (size_t)(p - (char*)d_ws);

    detect_idx_kernel<<<1, 256, 0, stream>>>(idx, flag, 4096, n_nodes);

    if (ws_size >= need && n_nodes <= 65535 && nbin <= NBINMAX) {
        // Binned path: bin-hist -> tiny scan -> binned scatter -> LDS accumulate
        hipMemsetAsync(cnt, 0, (size_t)2 * nbin * 4, stream);
        binhist_kernel<<<1024, 512, 0, stream>>>(idx, flag, cnt, nbin, n_edges);
        binscan_kernel<<<1, 64, 0, stream>>>(cnt, base, cur, 2 * nbin);
        binscatter_kernel<<<2048, 256, 0, stream>>>(idx, e, flag, cur, pay, nbin, n_edges);
        binacc_kernel<<<2 * nbin, 512, 0, stream>>>(x, pay, base, cnt, mi, mo, nbin, n_nodes);
    } else {
        // fallback: atomic scatter (measured 408 us)
        hipMemsetAsync(d_ws, 0, (size_t)2 * n_nodes * DD * sizeof(float), stream);
        scatter_kernel<<<4096, 256, 0, stream>>>(x, e, idx, flag, mi, mo, n_edges);
    }

    const int ngroups = (n_nodes + NPW - 1) / NPW;  // 3847 waves
    const int mblocks = (ngroups + 7) / 8;          // 481 blocks x 512 thr
    fused_mlp4<<<mblocks, 512, 0, stream>>>(
        mi, mo, x,
        W1, b1, g1, bt1, W2, b2, g2, bt2, W3, b3, g3, bt3, W4, b4, g4, bt4,
        out, n_nodes);
}